// Round 14
// baseline (1864.802 us; speedup 1.0000x reference)
//
#include <hip/hip_runtime.h>

typedef unsigned long long ull;
typedef _Float16 h4 __attribute__((ext_vector_type(4)));

constexpr int KK = 3;
constexpr int DBITS = 11;                  // dst bucket = 2048 nodes (2 blocks/CU)
constexpr int DB = 1 << DBITS;
constexpr int NPART = 256;                 // hist/partition blocks
constexpr int PBT = 1024;                  // hist/partition threads per block

__device__ __forceinline__ float relu_(float v) { return fmaxf(v, 0.f); }

// =================== build: hist -> scan -> partition ===================

__global__ __launch_bounds__(PBT) void hist_kernel(const int* __restrict__ col,
                                                   int* __restrict__ bh, int E, int nb) {
    __shared__ int h[1024];
    for (int i = threadIdx.x; i < nb; i += blockDim.x) h[i] = 0;
    __syncthreads();
    long e0 = (long)blockIdx.x * E / gridDim.x;
    long e1 = (long)(blockIdx.x + 1) * E / gridDim.x;
    for (long e = e0 + threadIdx.x; e < e1; e += blockDim.x)
        atomicAdd(&h[__builtin_nontemporal_load(col + e) >> DBITS], 1);
    __syncthreads();
    int* dst = bh + (size_t)blockIdx.x * nb;
    for (int i = threadIdx.x; i < nb; i += blockDim.x) dst[i] = h[i];
}

__global__ __launch_bounds__(NPART) void colscan_kernel(int* __restrict__ bh,
                                                        int* __restrict__ total, int nb) {
    __shared__ int sm[NPART];
    int i = blockIdx.x, tid = threadIdx.x;
    int v = bh[(size_t)tid * nb + i];
    sm[tid] = v;
    __syncthreads();
    for (int off = 1; off < NPART; off <<= 1) {
        int t = (tid >= off) ? sm[tid - off] : 0;
        __syncthreads();
        sm[tid] += t;
        __syncthreads();
    }
    bh[(size_t)tid * nb + i] = sm[tid] - v;
    if (tid == NPART - 1) total[i] = sm[tid];
}

__global__ __launch_bounds__(1024) void excl_scan_kernel(const int* __restrict__ total,
                                                         int* __restrict__ base, int nb, int E) {
    __shared__ int sm[1024];
    int tid = threadIdx.x;
    int v = (tid < nb) ? total[tid] : 0;
    sm[tid] = v;
    __syncthreads();
    for (int off = 1; off < 1024; off <<= 1) {
        int t = (tid >= off) ? sm[tid - off] : 0;
        __syncthreads();
        sm[tid] += t;
        __syncthreads();
    }
    if (tid < nb) base[tid] = sm[tid] - v;
    if (tid == 0) base[nb] = E;
}

// tmp[pos] = { (col_low11 << 20) | row20 , w_bits }   (needs N <= 2^20)
__global__ __launch_bounds__(PBT) void part_kernel(const int* __restrict__ row,
                                                   const int* __restrict__ col,
                                                   const float* __restrict__ w,
                                                   const int* __restrict__ cBase,
                                                   const int* __restrict__ bh,
                                                   uint2* __restrict__ tmp, int E, int nb) {
    __shared__ int cur[1024];
    const int* boff = bh + (size_t)blockIdx.x * nb;
    for (int i = threadIdx.x; i < nb; i += blockDim.x) cur[i] = cBase[i] + boff[i];
    __syncthreads();
    long e0 = (long)blockIdx.x * E / gridDim.x;
    long e1 = (long)(blockIdx.x + 1) * E / gridDim.x;
    for (long e = e0 + threadIdx.x; e < e1; e += blockDim.x) {
        int c = __builtin_nontemporal_load(col + e);
        int r = __builtin_nontemporal_load(row + e);
        float wv = __builtin_nontemporal_load(w + e);
        int b = c >> DBITS;
        int pos = atomicAdd(&cur[b], 1);
        uint2 t;
        t.x = ((unsigned)(c & (DB - 1)) << 20) | (unsigned)r;
        t.y = __float_as_uint(wv);
        tmp[pos] = t;
    }
}

// =================== bucket-stream compute (packed fp16 state) ===================
// tmp entry: { (cl<<20) | src , w_bits }, node = (blockIdx<<DBITS)+cl

__global__ __launch_bounds__(1024) void deg_kernel(const uint2* __restrict__ tmp,
                                                   const int* __restrict__ cBase,
                                                   const float* __restrict__ x,
                                                   float* __restrict__ dinv,
                                                   _Float16* __restrict__ xd, int N) {
    __shared__ float ws[DB];
    int bk = blockIdx.x, tid = threadIdx.x;
    for (int i = tid; i < DB; i += blockDim.x) ws[i] = 0.f;
    __syncthreads();
    long beg = cBase[bk], end = cBase[bk + 1];
    const ull* tp = (const ull*)tmp;
    for (long j = beg + tid; j < end; j += blockDim.x) {
        ull v = __builtin_nontemporal_load(tp + j);
        atomicAdd(&ws[((unsigned)v) >> 20], __uint_as_float((unsigned)(v >> 32)));
    }
    __syncthreads();
    for (int q = tid; q < DB; q += blockDim.x) {
        int node = (bk << DBITS) + q;
        if (node < N) {
            float s = ws[q];
            float di = (s > 0.f) ? rsqrtf(s) : 0.f;
            dinv[node] = di;
            xd[node] = (_Float16)(di * x[node]);
        }
    }
}

// Layer 0: scalar gather (xd), writes packed 3-stack state.
__global__ __launch_bounds__(1024) void layer0_kernel(const uint2* __restrict__ tmp,
                                                      const int* __restrict__ cBase,
                                                      const _Float16* __restrict__ xd,
                                                      const float* __restrict__ x,
                                                      const float* __restrict__ dinv,
                                                      const float* __restrict__ W,
                                                      const float* __restrict__ V,
                                                      const float* __restrict__ b,
                                                      h4* __restrict__ zd_out, int N) {
    __shared__ float acc[DB];
    int bk = blockIdx.x, tid = threadIdx.x;
    for (int i = tid; i < DB; i += blockDim.x) acc[i] = 0.f;
    __syncthreads();
    long beg = cBase[bk], end = cBase[bk + 1];
    const ull* tp = (const ull*)tmp;
    for (long j = beg + tid; j < end; j += blockDim.x) {
        ull v = __builtin_nontemporal_load(tp + j);
        unsigned key = (unsigned)v;
        float xv = (float)xd[key & 0xFFFFF];
        if (xv != 0.f)
            atomicAdd(&acc[key >> 20], __uint_as_float((unsigned)(v >> 32)) * xv);
    }
    __syncthreads();
    float W0 = W[0], W1 = W[1], W2 = W[2];
    float V0 = V[0], V1 = V[1], V2 = V[2];
    float b0 = b[0], b1 = b[1], b2 = b[2];
    for (int q = tid; q < DB; q += blockDim.x) {
        int node = (bk << DBITS) + q;
        if (node < N) {
            float di = dinv[node];
            float s = di * acc[q];
            float xi = x[node];
            h4 o;
            o[0] = (_Float16)(di * relu_(fmaf(W0, s, fmaf(V0, xi, b0))));
            o[1] = (_Float16)(di * relu_(fmaf(W1, s, fmaf(V1, xi, b1))));
            o[2] = (_Float16)(di * relu_(fmaf(W2, s, fmaf(V2, xi, b2))));
            o[3] = (_Float16)0.f;
            zd_out[node] = o;
        }
    }
}

// Mid/final layers: one packed gather feeds all 3 stacks.
// ReLU-sparsity skip: z_k == 0 (exactly, post-relu) contributes nothing -> no atomic.
// FINAL=0: zd_out[node] = packed dinv*relu(...)
// FINAL=1: outp[node] = sigmoid(lw*mean_k relu(...) + lb)
template <int FINAL>
__global__ __launch_bounds__(1024) void layerP_kernel(const uint2* __restrict__ tmp,
                                                      const int* __restrict__ cBase,
                                                      const h4* __restrict__ zd_in,
                                                      const float* __restrict__ x,
                                                      const float* __restrict__ dinv,
                                                      const float* __restrict__ W,
                                                      const float* __restrict__ V,
                                                      const float* __restrict__ b,
                                                      h4* __restrict__ zd_out,
                                                      const float* __restrict__ lin_w,
                                                      const float* __restrict__ lin_b,
                                                      float* __restrict__ outp, int N) {
    __shared__ float acc0[DB];
    __shared__ float acc1[DB];
    __shared__ float acc2[DB];
    int bk = blockIdx.x, tid = threadIdx.x;
    for (int i = tid; i < DB; i += blockDim.x) {
        acc0[i] = 0.f; acc1[i] = 0.f; acc2[i] = 0.f;
    }
    __syncthreads();
    long beg = cBase[bk], end = cBase[bk + 1];
    const ull* tp = (const ull*)tmp;
    for (long j = beg + tid; j < end; j += blockDim.x) {
        ull v = __builtin_nontemporal_load(tp + j);
        unsigned key = (unsigned)v;
        float wv = __uint_as_float((unsigned)(v >> 32));
        unsigned cl = key >> 20;
        h4 zv = zd_in[key & 0xFFFFF];
        float z0 = (float)zv[0], z1 = (float)zv[1], z2 = (float)zv[2];
        if (z0 != 0.f) atomicAdd(&acc0[cl], wv * z0);
        if (z1 != 0.f) atomicAdd(&acc1[cl], wv * z1);
        if (z2 != 0.f) atomicAdd(&acc2[cl], wv * z2);
    }
    __syncthreads();
    float W0 = W[0], W1 = W[1], W2 = W[2];
    float V0 = V[0], V1 = V[1], V2 = V[2];
    float b0 = b[0], b1 = b[1], b2 = b[2];
    for (int q = tid; q < DB; q += blockDim.x) {
        int node = (bk << DBITS) + q;
        if (node >= N) continue;
        float di = dinv[node];
        float xi = x[node];
        float h0 = relu_(fmaf(W0, di * acc0[q], fmaf(V0, xi, b0)));
        float h1 = relu_(fmaf(W1, di * acc1[q], fmaf(V1, xi, b1)));
        float h2 = relu_(fmaf(W2, di * acc2[q], fmaf(V2, xi, b2)));
        if (FINAL) {
            float m = (h0 + h1 + h2) * (1.f / 3.f);
            float z = fmaf(lin_w[0], m, lin_b[0]);
            outp[node] = 1.f / (1.f + __expf(-z));
        } else {
            h4 o;
            o[0] = (_Float16)(di * h0);
            o[1] = (_Float16)(di * h1);
            o[2] = (_Float16)(di * h2);
            o[3] = (_Float16)0.f;
            zd_out[node] = o;
        }
    }
}

// =================== fallback (push-atomic, any N/E) ===================

__global__ void fb_deg(const int* __restrict__ col, const float* __restrict__ w,
                       float* __restrict__ deg, int E) {
    int stride = gridDim.x * blockDim.x;
    for (int e = blockIdx.x * blockDim.x + threadIdx.x; e < E; e += stride)
        atomicAdd(&deg[col[e]], w[e]);
}
__global__ void fb_dinv(float* __restrict__ deg, int n) {
    int i = blockIdx.x * blockDim.x + threadIdx.x;
    if (i < n) { float d = deg[i]; deg[i] = (d > 0.f) ? rsqrtf(d) : 0.f; }
}
__global__ void fb_spmv(const int* __restrict__ row, const int* __restrict__ col,
                        const float* __restrict__ w, const float* __restrict__ dinv,
                        const float4* __restrict__ st, const float* __restrict__ x,
                        float* __restrict__ y4, int E, int useX) {
    int stride = gridDim.x * blockDim.x;
    for (int e = blockIdx.x * blockDim.x + threadIdx.x; e < E; e += stride) {
        int r = row[e], c = col[e];
        float nrm = dinv[r] * w[e] * dinv[c];
        if (useX) {
            atomicAdd(&y4[4 * c + 0], nrm * x[r]);
        } else {
            float4 v = st[r];
            atomicAdd(&y4[4 * c + 0], nrm * v.x);
            atomicAdd(&y4[4 * c + 1], nrm * v.y);
            atomicAdd(&y4[4 * c + 2], nrm * v.z);
        }
    }
}
__global__ void fb_epi(const float* __restrict__ y4, const float* __restrict__ x,
                       const float* __restrict__ W, const float* __restrict__ V,
                       const float* __restrict__ b, float4* __restrict__ out, int n, int bc) {
    int i = blockIdx.x * blockDim.x + threadIdx.x;
    if (i >= n) return;
    float xi = x[i];
    float4 o;
    o.x = relu_(fmaf(W[0], y4[4 * i + (bc ? 0 : 0)], fmaf(V[0], xi, b[0])));
    o.y = relu_(fmaf(W[1], y4[4 * i + (bc ? 0 : 1)], fmaf(V[1], xi, b[1])));
    o.z = relu_(fmaf(W[2], y4[4 * i + (bc ? 0 : 2)], fmaf(V[2], xi, b[2])));
    o.w = 0.f;
    out[i] = o;
}
__global__ void fb_final(const float4* __restrict__ out, const float* __restrict__ lin_w,
                         const float* __restrict__ lin_b, float* __restrict__ o, int n) {
    int i = blockIdx.x * blockDim.x + threadIdx.x;
    if (i >= n) return;
    float4 v = out[i];
    float m = (v.x + v.y + v.z) * (1.f / 3.f);
    float z = fmaf(lin_w[0], m, lin_b[0]);
    o[i] = 1.f / (1.f + __expf(-z));
}

// =================== launch ===================

extern "C" void kernel_launch(void* const* d_in, const int* in_sizes, int n_in,
                              void* d_out, int out_size, void* d_ws, size_t ws_size,
                              hipStream_t stream) {
    const float* x      = (const float*)d_in[0];
    const int*   eidx   = (const int*)d_in[1];
    const float* w      = (const float*)d_in[2];
    const float* initW  = (const float*)d_in[3];
    const float* weight = (const float*)d_in[4];
    const float* rootW  = (const float*)d_in[5];
    const float* bias   = (const float*)d_in[6];
    const float* lin_w  = (const float*)d_in[7];
    const float* lin_b  = (const float*)d_in[8];
    float* outp = (float*)d_out;

    const int N = in_sizes[0];
    const int E = in_sizes[2];
    const int* row = eidx;
    const int* col = eidx + (size_t)E;

    const int nb = (N + DB - 1) >> DBITS;    // 489 for N=1M

    auto align16 = [](size_t v) { return (v + 15) & ~(size_t)15; };

    // ---- primary: 2048-node dst buckets, packed fp16 3-stack state ----
    {
        size_t off = 0;
        size_t tmpOff   = off; off += align16((size_t)E * 8);            // uint2[E]
        size_t bhOff    = off; off += align16((size_t)NPART * nb * 4);
        size_t totOff   = off; off += align16((size_t)nb * 4);
        size_t cBOff    = off; off += align16((size_t)(nb + 1) * 4);
        size_t dinvOff  = off; off += align16((size_t)N * 4);
        size_t xdOff    = off; off += align16((size_t)N * 2);            // fp16
        size_t zAOff    = off; off += align16((size_t)N * 8);            // h4
        size_t zBOff    = off; off += align16((size_t)N * 8);            // h4
        size_t needed = off;

        if (ws_size >= needed && nb <= 1024 && N <= (1 << 20)) {
            char* wsb = (char*)d_ws;
            uint2* tmp  = (uint2*)(wsb + tmpOff);
            int*   bh   = (int*)(wsb + bhOff);
            int*   tot  = (int*)(wsb + totOff);
            int*   cB   = (int*)(wsb + cBOff);
            float* dinv = (float*)(wsb + dinvOff);
            _Float16* xd = (_Float16*)(wsb + xdOff);
            h4* zA = (h4*)(wsb + zAOff);
            h4* zB = (h4*)(wsb + zBOff);

            hist_kernel<<<NPART, PBT, 0, stream>>>(col, bh, E, nb);
            colscan_kernel<<<nb, NPART, 0, stream>>>(bh, tot, nb);
            excl_scan_kernel<<<1, 1024, 0, stream>>>(tot, cB, nb, E);
            part_kernel<<<NPART, PBT, 0, stream>>>(row, col, w, cB, bh, tmp, E, nb);

            deg_kernel<<<nb, 1024, 0, stream>>>(tmp, cB, x, dinv, xd, N);
            layer0_kernel<<<nb, 1024, 0, stream>>>(tmp, cB, xd, x, dinv, initW,
                                                   rootW + 0 * KK, bias + 0 * KK, zA, N);
            layerP_kernel<0><<<nb, 1024, 0, stream>>>(tmp, cB, zA, x, dinv,
                                                      weight + 0 * KK, rootW + 1 * KK,
                                                      bias + 1 * KK, zB,
                                                      nullptr, nullptr, nullptr, N);
            layerP_kernel<0><<<nb, 1024, 0, stream>>>(tmp, cB, zB, x, dinv,
                                                      weight + 1 * KK, rootW + 2 * KK,
                                                      bias + 2 * KK, zA,
                                                      nullptr, nullptr, nullptr, N);
            layerP_kernel<1><<<nb, 1024, 0, stream>>>(tmp, cB, zA, x, dinv,
                                                      weight + 2 * KK, rootW + 3 * KK,
                                                      bias + 3 * KK, nullptr,
                                                      lin_w, lin_b, outp, N);
            return;
        }
    }

    // ---- fallback: push-atomic path (correct for any N/E) ----
    {
        float* dinv = (float*)d_ws;
        float* y    = dinv + N;
        float4* st  = (float4*)(y + 4 * (size_t)N);
        const int TPB = 256;
        const int gridN = (N + TPB - 1) / TPB;

        hipMemsetAsync(dinv, 0, (size_t)N * 4, stream);
        fb_deg<<<8192, TPB, 0, stream>>>(col, w, dinv, E);
        fb_dinv<<<gridN, TPB, 0, stream>>>(dinv, N);

        hipMemsetAsync(y, 0, 4 * (size_t)N * 4, stream);
        fb_spmv<<<8192, TPB, 0, stream>>>(row, col, w, dinv, nullptr, x, y, E, 1);
        fb_epi<<<gridN, TPB, 0, stream>>>(y, x, initW, rootW + 0 * KK, bias + 0 * KK, st, N, 1);
        for (int t = 1; t < 4; ++t) {
            hipMemsetAsync(y, 0, 4 * (size_t)N * 4, stream);
            fb_spmv<<<8192, TPB, 0, stream>>>(row, col, w, dinv, st, nullptr, y, E, 0);
            fb_epi<<<gridN, TPB, 0, stream>>>(y, x, weight + (t - 1) * KK,
                                              rootW + t * KK, bias + t * KK, st, N, 0);
        }
        fb_final<<<gridN, TPB, 0, stream>>>(st, lin_w, lin_b, outp, N);
    }
}

// Round 15
// 1703.209 us; speedup vs baseline: 1.0949x; 1.0949x over previous
//
#include <hip/hip_runtime.h>

typedef unsigned long long ull;
typedef _Float16 h4 __attribute__((ext_vector_type(4)));

constexpr int KK = 3;
constexpr int DBITS = 12;                  // dst bucket = 4096 nodes
constexpr int DB = 1 << DBITS;
constexpr int NPART = 256;                 // hist/partition blocks
constexpr int PBT = 1024;                  // hist/partition threads per block
constexpr float FXS = 262144.f;            // 2^18 fixed-point scale
constexpr float FXI = 1.f / 262144.f;

__device__ __forceinline__ float relu_(float v) { return fmaxf(v, 0.f); }

// =================== build: hist -> scan -> partition ===================

__global__ __launch_bounds__(PBT) void hist_kernel(const int* __restrict__ col,
                                                   int* __restrict__ bh, int E, int nb) {
    __shared__ int h[1024];
    for (int i = threadIdx.x; i < nb; i += blockDim.x) h[i] = 0;
    __syncthreads();
    long e0 = (long)blockIdx.x * E / gridDim.x;
    long e1 = (long)(blockIdx.x + 1) * E / gridDim.x;
    for (long e = e0 + threadIdx.x; e < e1; e += blockDim.x)
        atomicAdd(&h[__builtin_nontemporal_load(col + e) >> DBITS], 1);
    __syncthreads();
    int* dst = bh + (size_t)blockIdx.x * nb;
    for (int i = threadIdx.x; i < nb; i += blockDim.x) dst[i] = h[i];
}

__global__ __launch_bounds__(NPART) void colscan_kernel(int* __restrict__ bh,
                                                        int* __restrict__ total, int nb) {
    __shared__ int sm[NPART];
    int i = blockIdx.x, tid = threadIdx.x;
    int v = bh[(size_t)tid * nb + i];
    sm[tid] = v;
    __syncthreads();
    for (int off = 1; off < NPART; off <<= 1) {
        int t = (tid >= off) ? sm[tid - off] : 0;
        __syncthreads();
        sm[tid] += t;
        __syncthreads();
    }
    bh[(size_t)tid * nb + i] = sm[tid] - v;
    if (tid == NPART - 1) total[i] = sm[tid];
}

__global__ __launch_bounds__(1024) void excl_scan_kernel(const int* __restrict__ total,
                                                         int* __restrict__ base, int nb, int E) {
    __shared__ int sm[1024];
    int tid = threadIdx.x;
    int v = (tid < nb) ? total[tid] : 0;
    sm[tid] = v;
    __syncthreads();
    for (int off = 1; off < 1024; off <<= 1) {
        int t = (tid >= off) ? sm[tid - off] : 0;
        __syncthreads();
        sm[tid] += t;
        __syncthreads();
    }
    if (tid < nb) base[tid] = sm[tid] - v;
    if (tid == 0) base[nb] = E;
}

// tmp[pos] = { (col_low12 << 20) | row20 , w_bits }   (needs N <= 2^20)
__global__ __launch_bounds__(PBT) void part_kernel(const int* __restrict__ row,
                                                   const int* __restrict__ col,
                                                   const float* __restrict__ w,
                                                   const int* __restrict__ cBase,
                                                   const int* __restrict__ bh,
                                                   uint2* __restrict__ tmp, int E, int nb) {
    __shared__ int cur[1024];
    const int* boff = bh + (size_t)blockIdx.x * nb;
    for (int i = threadIdx.x; i < nb; i += blockDim.x) cur[i] = cBase[i] + boff[i];
    __syncthreads();
    long e0 = (long)blockIdx.x * E / gridDim.x;
    long e1 = (long)(blockIdx.x + 1) * E / gridDim.x;
    for (long e = e0 + threadIdx.x; e < e1; e += blockDim.x) {
        int c = __builtin_nontemporal_load(col + e);
        int r = __builtin_nontemporal_load(row + e);
        float wv = __builtin_nontemporal_load(w + e);
        int b = c >> DBITS;
        int pos = atomicAdd(&cur[b], 1);
        uint2 t;
        t.x = ((unsigned)(c & (DB - 1)) << 20) | (unsigned)r;
        t.y = __float_as_uint(wv);
        tmp[pos] = t;
    }
}

// =================== bucket-stream compute (packed fp16 state) ===================
// tmp entry: { (cl<<20) | src , w_bits }, node = (blockIdx<<DBITS)+cl

__global__ __launch_bounds__(1024) void deg_kernel(const uint2* __restrict__ tmp,
                                                   const int* __restrict__ cBase,
                                                   const float* __restrict__ x,
                                                   float* __restrict__ dinv,
                                                   _Float16* __restrict__ xd, int N) {
    __shared__ float ws[DB];
    int bk = blockIdx.x, tid = threadIdx.x;
    for (int i = tid; i < DB; i += blockDim.x) ws[i] = 0.f;
    __syncthreads();
    long beg = cBase[bk], end = cBase[bk + 1];
    const ull* tp = (const ull*)tmp;
    for (long j = beg + tid; j < end; j += blockDim.x) {
        ull v = __builtin_nontemporal_load(tp + j);
        atomicAdd(&ws[((unsigned)v) >> 20], __uint_as_float((unsigned)(v >> 32)));
    }
    __syncthreads();
    for (int q = tid; q < DB; q += blockDim.x) {
        int node = (bk << DBITS) + q;
        if (node < N) {
            float s = ws[q];
            float di = (s > 0.f) ? rsqrtf(s) : 0.f;
            dinv[node] = di;
            xd[node] = (_Float16)(di * x[node]);
        }
    }
}

// Layer 0: scalar gather (xd), writes packed 3-stack state.
__global__ __launch_bounds__(1024) void layer0_kernel(const uint2* __restrict__ tmp,
                                                      const int* __restrict__ cBase,
                                                      const _Float16* __restrict__ xd,
                                                      const float* __restrict__ x,
                                                      const float* __restrict__ dinv,
                                                      const float* __restrict__ W,
                                                      const float* __restrict__ V,
                                                      const float* __restrict__ b,
                                                      h4* __restrict__ zd_out, int N) {
    __shared__ float acc[DB];
    int bk = blockIdx.x, tid = threadIdx.x;
    for (int i = tid; i < DB; i += blockDim.x) acc[i] = 0.f;
    __syncthreads();
    long beg = cBase[bk], end = cBase[bk + 1];
    const ull* tp = (const ull*)tmp;
    for (long j = beg + tid; j < end; j += blockDim.x) {
        ull v = __builtin_nontemporal_load(tp + j);
        unsigned key = (unsigned)v;
        float xv = (float)xd[key & 0xFFFFF];
        if (xv != 0.f)
            atomicAdd(&acc[key >> 20], __uint_as_float((unsigned)(v >> 32)) * xv);
    }
    __syncthreads();
    float W0 = W[0], W1 = W[1], W2 = W[2];
    float V0 = V[0], V1 = V[1], V2 = V[2];
    float b0 = b[0], b1 = b[1], b2 = b[2];
    for (int q = tid; q < DB; q += blockDim.x) {
        int node = (bk << DBITS) + q;
        if (node < N) {
            float di = dinv[node];
            float s = di * acc[q];
            float xi = x[node];
            h4 o;
            o[0] = (_Float16)(di * relu_(fmaf(W0, s, fmaf(V0, xi, b0))));
            o[1] = (_Float16)(di * relu_(fmaf(W1, s, fmaf(V1, xi, b1))));
            o[2] = (_Float16)(di * relu_(fmaf(W2, s, fmaf(V2, xi, b2))));
            o[3] = (_Float16)0.f;
            zd_out[node] = o;
        }
    }
}

// Mid/final layers: one packed gather feeds all 3 stacks.
// Channels 0,1 accumulate as carry-free Q?.18 fixed-point halves of one u64 LDS
// atomic (all contributions >= 0); channel 2 stays fp32. ReLU-zero groups skipped.
// FINAL=0: zd_out[node] = packed dinv*relu(...)
// FINAL=1: outp[node] = sigmoid(lw*mean_k relu(...) + lb)
template <int FINAL>
__global__ __launch_bounds__(1024) void layerP_kernel(const uint2* __restrict__ tmp,
                                                      const int* __restrict__ cBase,
                                                      const h4* __restrict__ zd_in,
                                                      const float* __restrict__ x,
                                                      const float* __restrict__ dinv,
                                                      const float* __restrict__ W,
                                                      const float* __restrict__ V,
                                                      const float* __restrict__ b,
                                                      h4* __restrict__ zd_out,
                                                      const float* __restrict__ lin_w,
                                                      const float* __restrict__ lin_b,
                                                      float* __restrict__ outp, int N) {
    __shared__ ull acc01[DB];      // 32 KB: ch0 in low 32b, ch1 in high 32b (Q.18)
    __shared__ float acc2[DB];     // 16 KB
    int bk = blockIdx.x, tid = threadIdx.x;
    for (int i = tid; i < DB; i += blockDim.x) {
        acc01[i] = 0ull;
        acc2[i] = 0.f;
    }
    __syncthreads();
    long beg = cBase[bk], end = cBase[bk + 1];
    const ull* tp = (const ull*)tmp;
    for (long j = beg + tid; j < end; j += blockDim.x) {
        ull v = __builtin_nontemporal_load(tp + j);
        unsigned key = (unsigned)v;
        float wv = __uint_as_float((unsigned)(v >> 32));
        unsigned cl = key >> 20;
        h4 zv = zd_in[key & 0xFFFFF];
        float p0 = wv * (float)zv[0];
        float p1 = wv * (float)zv[1];
        float p2 = wv * (float)zv[2];
        if (p0 != 0.f || p1 != 0.f) {
            unsigned q0 = (unsigned)(p0 * FXS + 0.5f);
            unsigned q1 = (unsigned)(p1 * FXS + 0.5f);
            atomicAdd(&acc01[cl], ((ull)q1 << 32) | (ull)q0);
        }
        if (p2 != 0.f) atomicAdd(&acc2[cl], p2);
    }
    __syncthreads();
    float W0 = W[0], W1 = W[1], W2 = W[2];
    float V0 = V[0], V1 = V[1], V2 = V[2];
    float b0 = b[0], b1 = b[1], b2 = b[2];
    for (int q = tid; q < DB; q += blockDim.x) {
        int node = (bk << DBITS) + q;
        if (node >= N) continue;
        ull a = acc01[q];
        float s0 = (float)(unsigned)(a & 0xFFFFFFFFull) * FXI;
        float s1 = (float)(unsigned)(a >> 32) * FXI;
        float s2 = acc2[q];
        float di = dinv[node];
        float xi = x[node];
        float h0 = relu_(fmaf(W0, di * s0, fmaf(V0, xi, b0)));
        float h1 = relu_(fmaf(W1, di * s1, fmaf(V1, xi, b1)));
        float h2 = relu_(fmaf(W2, di * s2, fmaf(V2, xi, b2)));
        if (FINAL) {
            float m = (h0 + h1 + h2) * (1.f / 3.f);
            float z = fmaf(lin_w[0], m, lin_b[0]);
            outp[node] = 1.f / (1.f + __expf(-z));
        } else {
            h4 o;
            o[0] = (_Float16)(di * h0);
            o[1] = (_Float16)(di * h1);
            o[2] = (_Float16)(di * h2);
            o[3] = (_Float16)0.f;
            zd_out[node] = o;
        }
    }
}

// =================== fallback (push-atomic, any N/E) ===================

__global__ void fb_deg(const int* __restrict__ col, const float* __restrict__ w,
                       float* __restrict__ deg, int E) {
    int stride = gridDim.x * blockDim.x;
    for (int e = blockIdx.x * blockDim.x + threadIdx.x; e < E; e += stride)
        atomicAdd(&deg[col[e]], w[e]);
}
__global__ void fb_dinv(float* __restrict__ deg, int n) {
    int i = blockIdx.x * blockDim.x + threadIdx.x;
    if (i < n) { float d = deg[i]; deg[i] = (d > 0.f) ? rsqrtf(d) : 0.f; }
}
__global__ void fb_spmv(const int* __restrict__ row, const int* __restrict__ col,
                        const float* __restrict__ w, const float* __restrict__ dinv,
                        const float4* __restrict__ st, const float* __restrict__ x,
                        float* __restrict__ y4, int E, int useX) {
    int stride = gridDim.x * blockDim.x;
    for (int e = blockIdx.x * blockDim.x + threadIdx.x; e < E; e += stride) {
        int r = row[e], c = col[e];
        float nrm = dinv[r] * w[e] * dinv[c];
        if (useX) {
            atomicAdd(&y4[4 * c + 0], nrm * x[r]);
        } else {
            float4 v = st[r];
            atomicAdd(&y4[4 * c + 0], nrm * v.x);
            atomicAdd(&y4[4 * c + 1], nrm * v.y);
            atomicAdd(&y4[4 * c + 2], nrm * v.z);
        }
    }
}
__global__ void fb_epi(const float* __restrict__ y4, const float* __restrict__ x,
                       const float* __restrict__ W, const float* __restrict__ V,
                       const float* __restrict__ b, float4* __restrict__ out, int n, int bc) {
    int i = blockIdx.x * blockDim.x + threadIdx.x;
    if (i >= n) return;
    float xi = x[i];
    float4 o;
    o.x = relu_(fmaf(W[0], y4[4 * i + (bc ? 0 : 0)], fmaf(V[0], xi, b[0])));
    o.y = relu_(fmaf(W[1], y4[4 * i + (bc ? 0 : 1)], fmaf(V[1], xi, b[1])));
    o.z = relu_(fmaf(W[2], y4[4 * i + (bc ? 0 : 2)], fmaf(V[2], xi, b[2])));
    o.w = 0.f;
    out[i] = o;
}
__global__ void fb_final(const float4* __restrict__ out, const float* __restrict__ lin_w,
                         const float* __restrict__ lin_b, float* __restrict__ o, int n) {
    int i = blockIdx.x * blockDim.x + threadIdx.x;
    if (i >= n) return;
    float4 v = out[i];
    float m = (v.x + v.y + v.z) * (1.f / 3.f);
    float z = fmaf(lin_w[0], m, lin_b[0]);
    o[i] = 1.f / (1.f + __expf(-z));
}

// =================== launch ===================

extern "C" void kernel_launch(void* const* d_in, const int* in_sizes, int n_in,
                              void* d_out, int out_size, void* d_ws, size_t ws_size,
                              hipStream_t stream) {
    const float* x      = (const float*)d_in[0];
    const int*   eidx   = (const int*)d_in[1];
    const float* w      = (const float*)d_in[2];
    const float* initW  = (const float*)d_in[3];
    const float* weight = (const float*)d_in[4];
    const float* rootW  = (const float*)d_in[5];
    const float* bias   = (const float*)d_in[6];
    const float* lin_w  = (const float*)d_in[7];
    const float* lin_b  = (const float*)d_in[8];
    float* outp = (float*)d_out;

    const int N = in_sizes[0];
    const int E = in_sizes[2];
    const int* row = eidx;
    const int* col = eidx + (size_t)E;

    const int nb = (N + DB - 1) >> DBITS;    // 245 for N=1M

    auto align16 = [](size_t v) { return (v + 15) & ~(size_t)15; };

    // ---- primary: 4096-node dst buckets, packed fp16 3-stack state ----
    {
        size_t off = 0;
        size_t tmpOff   = off; off += align16((size_t)E * 8);            // uint2[E]
        size_t bhOff    = off; off += align16((size_t)NPART * nb * 4);
        size_t totOff   = off; off += align16((size_t)nb * 4);
        size_t cBOff    = off; off += align16((size_t)(nb + 1) * 4);
        size_t dinvOff  = off; off += align16((size_t)N * 4);
        size_t xdOff    = off; off += align16((size_t)N * 2);            // fp16
        size_t zAOff    = off; off += align16((size_t)N * 8);            // h4
        size_t zBOff    = off; off += align16((size_t)N * 8);            // h4
        size_t needed = off;

        if (ws_size >= needed && nb <= 1024 && N <= (1 << 20)) {
            char* wsb = (char*)d_ws;
            uint2* tmp  = (uint2*)(wsb + tmpOff);
            int*   bh   = (int*)(wsb + bhOff);
            int*   tot  = (int*)(wsb + totOff);
            int*   cB   = (int*)(wsb + cBOff);
            float* dinv = (float*)(wsb + dinvOff);
            _Float16* xd = (_Float16*)(wsb + xdOff);
            h4* zA = (h4*)(wsb + zAOff);
            h4* zB = (h4*)(wsb + zBOff);

            hist_kernel<<<NPART, PBT, 0, stream>>>(col, bh, E, nb);
            colscan_kernel<<<nb, NPART, 0, stream>>>(bh, tot, nb);
            excl_scan_kernel<<<1, 1024, 0, stream>>>(tot, cB, nb, E);
            part_kernel<<<NPART, PBT, 0, stream>>>(row, col, w, cB, bh, tmp, E, nb);

            deg_kernel<<<nb, 1024, 0, stream>>>(tmp, cB, x, dinv, xd, N);
            layer0_kernel<<<nb, 1024, 0, stream>>>(tmp, cB, xd, x, dinv, initW,
                                                   rootW + 0 * KK, bias + 0 * KK, zA, N);
            layerP_kernel<0><<<nb, 1024, 0, stream>>>(tmp, cB, zA, x, dinv,
                                                      weight + 0 * KK, rootW + 1 * KK,
                                                      bias + 1 * KK, zB,
                                                      nullptr, nullptr, nullptr, N);
            layerP_kernel<0><<<nb, 1024, 0, stream>>>(tmp, cB, zB, x, dinv,
                                                      weight + 1 * KK, rootW + 2 * KK,
                                                      bias + 2 * KK, zA,
                                                      nullptr, nullptr, nullptr, N);
            layerP_kernel<1><<<nb, 1024, 0, stream>>>(tmp, cB, zA, x, dinv,
                                                      weight + 2 * KK, rootW + 3 * KK,
                                                      bias + 3 * KK, nullptr,
                                                      lin_w, lin_b, outp, N);
            return;
        }
    }

    // ---- fallback: push-atomic path (correct for any N/E) ----
    {
        float* dinv = (float*)d_ws;
        float* y    = dinv + N;
        float4* st  = (float4*)(y + 4 * (size_t)N);
        const int TPB = 256;
        const int gridN = (N + TPB - 1) / TPB;

        hipMemsetAsync(dinv, 0, (size_t)N * 4, stream);
        fb_deg<<<8192, TPB, 0, stream>>>(col, w, dinv, E);
        fb_dinv<<<gridN, TPB, 0, stream>>>(dinv, N);

        hipMemsetAsync(y, 0, 4 * (size_t)N * 4, stream);
        fb_spmv<<<8192, TPB, 0, stream>>>(row, col, w, dinv, nullptr, x, y, E, 1);
        fb_epi<<<gridN, TPB, 0, stream>>>(y, x, initW, rootW + 0 * KK, bias + 0 * KK, st, N, 1);
        for (int t = 1; t < 4; ++t) {
            hipMemsetAsync(y, 0, 4 * (size_t)N * 4, stream);
            fb_spmv<<<8192, TPB, 0, stream>>>(row, col, w, dinv, st, nullptr, y, E, 0);
            fb_epi<<<gridN, TPB, 0, stream>>>(y, x, weight + (t - 1) * KK,
                                              rootW + t * KK, bias + t * KK, st, N, 0);
        }
        fb_final<<<gridN, TPB, 0, stream>>>(st, lin_w, lin_b, outp, N);
    }
}